// Round 5
// baseline (127.288 us; speedup 1.0000x reference)
//
#include <hip/hip_runtime.h>
#include <math.h>

#define NB      8192
#define HLEN    200
#define DIM     128
#define AH      64
#define NITEMS  100000
#define NTILE   13
#define INTER_BLKS (NB / 32)

typedef __attribute__((ext_vector_type(4))) float f32x4;
typedef __attribute__((ext_vector_type(2))) float f32x2;
typedef __attribute__((ext_vector_type(4))) int   i32x4;
typedef __attribute__((ext_vector_type(8))) short bf16x8;
typedef unsigned int uint;

__device__ __forceinline__ unsigned short f2bf(float f) {
  uint u = __float_as_uint(f);
  u += 0x7fffu + ((u >> 16) & 1u);
  return (unsigned short)(u >> 16);
}
__device__ __forceinline__ float bf2f(unsigned short h) {
  return __uint_as_float(((uint)h) << 16);
}
__device__ __forceinline__ long pick64(const i32x4& v, int h) {
  return (long)(unsigned)v[2 * h] | ((long)(unsigned)v[2 * h + 1] << 32);
}

// ---------------------------------------------------------------------------
// Pre-kernel: blocks [0,INTER_BLKS) = bilinear interaction + item_emb copy;
// rest = item_table f32 -> fp8 e4m3 (row = 128B = one line) + w1 -> fp8
// A-operand table for the SWAPPED mfma (D[ah][row] = W1^T · hist^T):
//   w1a8[part*8192 + s*2048 + nt*512 + m*32 + g*8 + j]
//     = fp8( w1[ part*128 + dim(s,g,j) ][ nt*16 + m ] ),
//   dim(s,g,j) = (s>>1)*64 + g*16 + (s&1)*8 + j   (bijective per step s)
// ---------------------------------------------------------------------------
__global__ __launch_bounds__(256)
void pre_kernel(const int* __restrict__ user_ids,
                const int* __restrict__ item_ids,
                const float* __restrict__ user_table,
                const float* __restrict__ item_table,
                const float* __restrict__ fi,
                const float* __restrict__ w1,
                unsigned char* __restrict__ tbl8,
                unsigned char* __restrict__ w1a8,
                float* __restrict__ out_item,
                float* __restrict__ out_inter) {
  const int t = threadIdx.x;
  if (blockIdx.x < INTER_BLKS) {
    // ---------------- bilinear interaction (verified r1-r3 body) ----------
    __shared__ unsigned short fitb[DIM * 130];
    __shared__ float u4[4][DIM];
    __shared__ float red[4][4];
    for (int i = t; i < DIM * DIM; i += 256) {
      int d = i >> 7, e = i & 127;
      fitb[e * 130 + d] = f2bf(fi[i]);
    }
    const int col = t & 127;
    const int dh = t >> 7;
    const int lane = t & 63;
    const int wv = t >> 6;
    const int b0 = blockIdx.x * 32;
    const unsigned short* fr = &fitb[col * 130 + dh * 64];
    for (int grp = 0; grp < 8; ++grp) {
      __syncthreads();
      for (int i = t; i < 4 * DIM; i += 256) {
        int bi = i >> 7, d = i & 127;
        u4[bi][d] = user_table[(long)user_ids[b0 + grp * 4 + bi] * DIM + d];
      }
      __syncthreads();
      float a0 = 0.f, a1 = 0.f, a2 = 0.f, a3 = 0.f;
#pragma unroll 4
      for (int d = 0; d < 64; d += 4) {
        float f0 = bf2f(fr[d]), f1 = bf2f(fr[d + 1]), f2 = bf2f(fr[d + 2]), f3 = bf2f(fr[d + 3]);
        f32x4 q0 = *(const f32x4*)&u4[0][dh * 64 + d];
        f32x4 q1 = *(const f32x4*)&u4[1][dh * 64 + d];
        f32x4 q2 = *(const f32x4*)&u4[2][dh * 64 + d];
        f32x4 q3 = *(const f32x4*)&u4[3][dh * 64 + d];
        a0 = fmaf(f0, q0[0], a0); a0 = fmaf(f1, q0[1], a0); a0 = fmaf(f2, q0[2], a0); a0 = fmaf(f3, q0[3], a0);
        a1 = fmaf(f0, q1[0], a1); a1 = fmaf(f1, q1[1], a1); a1 = fmaf(f2, q1[2], a1); a1 = fmaf(f3, q1[3], a1);
        a2 = fmaf(f0, q2[0], a2); a2 = fmaf(f1, q2[1], a2); a2 = fmaf(f2, q2[2], a2); a2 = fmaf(f3, q2[3], a2);
        a3 = fmaf(f0, q3[0], a3); a3 = fmaf(f1, q3[1], a3); a3 = fmaf(f2, q3[2], a3); a3 = fmaf(f3, q3[3], a3);
      }
      const int bb = b0 + grp * 4;
      const float vv0 = item_table[(long)item_ids[bb + 0] * DIM + col];
      const float vv1 = item_table[(long)item_ids[bb + 1] * DIM + col];
      const float vv2 = item_table[(long)item_ids[bb + 2] * DIM + col];
      const float vv3 = item_table[(long)item_ids[bb + 3] * DIM + col];
      if (dh == 0) {
        out_item[(long)(bb + 0) * DIM + col] = vv0;
        out_item[(long)(bb + 1) * DIM + col] = vv1;
        out_item[(long)(bb + 2) * DIM + col] = vv2;
        out_item[(long)(bb + 3) * DIM + col] = vv3;
      }
      float p0 = a0 * vv0, p1 = a1 * vv1, p2 = a2 * vv2, p3 = a3 * vv3;
#pragma unroll
      for (int msk = 1; msk <= 32; msk <<= 1) {
        p0 += __shfl_xor(p0, msk);
        p1 += __shfl_xor(p1, msk);
        p2 += __shfl_xor(p2, msk);
        p3 += __shfl_xor(p3, msk);
      }
      if (lane == 0) { red[wv][0] = p0; red[wv][1] = p1; red[wv][2] = p2; red[wv][3] = p3; }
      __syncthreads();
      if (t < 4)
        out_inter[bb + t] = red[0][t] + red[1][t] + red[2][t] + red[3][t];
    }
  } else {
    const int cb = blockIdx.x - INTER_BLKS;
    const int cgrid = gridDim.x - INTER_BLKS;
    const long t0 = (long)cb * 256 + t;
    const long total4 = (long)NITEMS * DIM / 4;
    const long stride = (long)cgrid * 256;
    for (long i = t0; i < total4; i += stride) {
      f32x4 v = ((const f32x4*)item_table)[i];
      int p = __builtin_amdgcn_cvt_pk_fp8_f32(v[0], v[1], 0, false);
      p     = __builtin_amdgcn_cvt_pk_fp8_f32(v[2], v[3], p, true);
      ((int*)tbl8)[i] = p;
    }
    if (t0 < 16384) {
      int L = (int)t0;
      int j = L & 7, g = (L >> 3) & 3, m = (L >> 5) & 15;
      int nt = (L >> 9) & 3, s = (L >> 11) & 3, part = (L >> 13) & 1;
      int dim = (s >> 1) * 64 + g * 16 + (s & 1) * 8 + j;
      float v = w1[(part * 128 + dim) * AH + nt * 16 + m];
      int pk = __builtin_amdgcn_cvt_pk_fp8_f32(v, v, 0, false);
      w1a8[L] = (unsigned char)(pk & 0xff);
    }
  }
}

// ---------------------------------------------------------------------------
// Main kernel: swapped-operand fp8 MFMA attention pooling.
// D[ah][row] = W1^T · hist^T  -> score lands with row = lane m; reduce is
// only 2 shfl_xor. Accumulator seeded with ub (= u@W1top + b1).
// 4-buffer ring, prefetch distance 3 (consumer buf t&3 never aliases the
// prefetch target (t+3)&3 -- the r4 bug was distance 4 == ring size).
// ---------------------------------------------------------------------------
__global__ __launch_bounds__(256)
void main_kernel_fp8s(const int* __restrict__ user_ids,
                      const int* __restrict__ user_history,
                      const float* __restrict__ user_table,
                      const unsigned char* __restrict__ tbl8,
                      const unsigned char* __restrict__ w1a8,
                      const float* __restrict__ b1,
                      const float* __restrict__ w2,
                      const float* __restrict__ b2,
                      float* __restrict__ out_user) {
  const int lane = threadIdx.x & 63;
  const int wave = threadIdx.x >> 6;
  const int b = blockIdx.x * 4 + wave;
  const int m = lane & 15;
  const int g = lane >> 4;

  const int uid = __builtin_amdgcn_readfirstlane(user_ids[b]);
  const float* urow = user_table + (long)uid * DIM;
  const int* hrow = user_history + (long)b * HLEN;

  // ---- preload ALL history indices upfront (13 independent loads) ----
  int idxs[NTILE];
#pragma unroll
  for (int t = 0; t < NTILE; ++t) {
    int row = t * 16 + m;
    idxs[t] = (row < HLEN) ? hrow[row] : 0;
  }

  // ---- gather ring: 4 buffers, distance 3 ----
  i32x4 pa[4][2];
#define LOADT(T, BUF)                                                          \
  {                                                                            \
    const unsigned char* p_ = tbl8 + ((long)idxs[T] << 7) + g * 16;            \
    pa[BUF][0] = *(const i32x4*)p_;                                            \
    pa[BUF][1] = *(const i32x4*)(p_ + 64);                                     \
  }
  LOADT(0, 0) LOADT(1, 1) LOADT(2, 2)

  // ---- u as fp8 B-operand fragments (same (g,j)->dim map as rows) ----
  long ufr[4];
#pragma unroll
  for (int s = 0; s < 4; ++s) {
    const float* up = urow + (s >> 1) * 64 + g * 16 + (s & 1) * 8;
    f32x4 qa = *(const f32x4*)up;
    f32x4 qb = *(const f32x4*)(up + 4);
    int d0 = __builtin_amdgcn_cvt_pk_fp8_f32(qa[0], qa[1], 0, false);
    d0     = __builtin_amdgcn_cvt_pk_fp8_f32(qa[2], qa[3], d0, true);
    int d1 = __builtin_amdgcn_cvt_pk_fp8_f32(qb[0], qb[1], 0, false);
    d1     = __builtin_amdgcn_cvt_pk_fp8_f32(qb[2], qb[3], d1, true);
    ufr[s] = (long)(uint)d0 | ((long)(uint)d1 << 32);
  }

  // ---- u-projection (swapped): accu[nt][r] = (u@W1top)[nt*16+g*4+r] ----
  f32x4 accu[4];
#pragma unroll
  for (int nt = 0; nt < 4; ++nt) accu[nt] = (f32x4){0.f, 0.f, 0.f, 0.f};
#pragma unroll
  for (int s = 0; s < 4; ++s) {
#pragma unroll
    for (int nt = 0; nt < 4; ++nt) {
      long wa = *(const long*)(w1a8 + ((s * 4 + nt) * 16 + m) * 32 + g * 8);
      accu[nt] = __builtin_amdgcn_mfma_f32_16x16x32_fp8_fp8(wa, ufr[s], accu[nt], 0, 0, 0);
    }
  }
  float ub2[4][4], w2v[4][4];
#pragma unroll
  for (int nt = 0; nt < 4; ++nt)
#pragma unroll
    for (int r = 0; r < 4; ++r) {
      const int ah = nt * 16 + g * 4 + r;
      ub2[nt][r] = accu[nt][r] + b1[ah];
      w2v[nt][r] = w2[ah];
    }
  const float b2v = b2[0];

  // ---- W1 bottom A-fragments held in registers ----
  long wb[4][4];
#pragma unroll
  for (int s = 0; s < 4; ++s)
#pragma unroll
    for (int nt = 0; nt < 4; ++nt)
      wb[s][nt] = *(const long*)(w1a8 + 8192 + ((s * 4 + nt) * 16 + m) * 32 + g * 8);

  float arep[32];
#pragma unroll
  for (int c = 0; c < 32; ++c) arep[c] = 0.f;

#pragma unroll
  for (int t = 0; t < NTILE; ++t) {
    if (t + 3 < NTILE) LOADT(t + 3, (t + 3) & 3)
    const int cb = t & 3;

    // scores with bias pre-seeded in the accumulator
    f32x4 acc[4];
#pragma unroll
    for (int nt = 0; nt < 4; ++nt)
      acc[nt] = (f32x4){ub2[nt][0], ub2[nt][1], ub2[nt][2], ub2[nt][3]};
#pragma unroll
    for (int s = 0; s < 4; ++s) {
      long bs = pick64(pa[cb][s >> 1], s & 1);
#pragma unroll
      for (int nt = 0; nt < 4; ++nt)
        acc[nt] = __builtin_amdgcn_mfma_f32_16x16x32_fp8_fp8(wb[s][nt], bs, acc[nt], 0, 0, 0);
    }

    // relu . w2 : 4 independent chains + 2-level tree, then 2 shfl_xor
    float cn[4];
#pragma unroll
    for (int nt = 0; nt < 4; ++nt) {
      float c = fmaxf(acc[nt][0], 0.f) * w2v[nt][0];
      c = fmaf(fmaxf(acc[nt][1], 0.f), w2v[nt][1], c);
      c = fmaf(fmaxf(acc[nt][2], 0.f), w2v[nt][2], c);
      c = fmaf(fmaxf(acc[nt][3], 0.f), w2v[nt][3], c);
      cn[nt] = c;
    }
    float sl = (cn[0] + cn[1]) + (cn[2] + cn[3]);
    sl += __shfl_xor(sl, 16);
    sl += __shfl_xor(sl, 32);
    float attw = 1.f / (1.f + __expf(-(sl + b2v)));
    if (t * 16 + m >= HLEN) attw = 0.f;

    // weighted accumulate (fp8 decode of the already-loaded row bytes)
#pragma unroll
    for (int kb = 0; kb < 2; ++kb)
#pragma unroll
      for (int d = 0; d < 4; ++d) {
        f32x2 lo = __builtin_amdgcn_cvt_pk_f32_fp8(pa[cb][kb][d], false);
        f32x2 hi = __builtin_amdgcn_cvt_pk_f32_fp8(pa[cb][kb][d], true);
        const int base = kb * 16 + d * 4;
        arep[base + 0] = fmaf(attw, lo[0], arep[base + 0]);
        arep[base + 1] = fmaf(attw, lo[1], arep[base + 1]);
        arep[base + 2] = fmaf(attw, hi[0], arep[base + 2]);
        arep[base + 3] = fmaf(attw, hi[1], arep[base + 3]);
      }
  }
#undef LOADT

  // reduce over the 16 row-lanes; lane m==0 of each group writes 32 cols
#pragma unroll
  for (int c = 0; c < 32; ++c) {
    arep[c] += __shfl_xor(arep[c], 1);
    arep[c] += __shfl_xor(arep[c], 2);
    arep[c] += __shfl_xor(arep[c], 4);
    arep[c] += __shfl_xor(arep[c], 8);
  }
  if (m == 0) {
#pragma unroll
    for (int kb = 0; kb < 2; ++kb)
#pragma unroll
      for (int i4 = 0; i4 < 4; ++i4) {
        const int col = kb * 64 + g * 16 + i4 * 4;
        f32x4 uv = *(const f32x4*)(urow + col);
        f32x4 o;
#pragma unroll
        for (int qq = 0; qq < 4; ++qq) o[qq] = uv[qq] + arep[kb * 16 + i4 * 4 + qq];
        *(f32x4*)(out_user + (long)b * DIM + col) = o;
      }
  }
}

// ---------------------------------------------------------------------------
// Fallback (ws too small): r1 bf16-inline path, f32 table reads (verified).
// ---------------------------------------------------------------------------
__global__ __launch_bounds__(256)
void main_fallback(const int* __restrict__ user_ids,
                   const int* __restrict__ user_history,
                   const float* __restrict__ user_table,
                   const float* __restrict__ item_table,
                   const float* __restrict__ w1,
                   const float* __restrict__ b1,
                   const float* __restrict__ w2,
                   const float* __restrict__ b2,
                   float* __restrict__ out_user) {
  const int lane = threadIdx.x & 63;
  const int wave = threadIdx.x >> 6;
  const int b = blockIdx.x * 4 + wave;
  const int m = lane & 15, g = lane >> 4;
  const int uid = __builtin_amdgcn_readfirstlane(user_ids[b]);
  const float* urow = user_table + (long)uid * DIM;
  float upj = b1[lane];
#pragma unroll 8
  for (int d = 0; d < DIM; ++d) upj = fmaf(urow[d], w1[d * AH + lane], upj);
  bf16x8 bfr[4][4];
#pragma unroll
  for (int ks = 0; ks < 4; ++ks)
#pragma unroll
    for (int nt = 0; nt < 4; ++nt) {
      bf16x8 bv;
#pragma unroll
      for (int j = 0; j < 8; ++j)
        bv[j] = (short)f2bf(w1[(DIM + ks * 32 + g * 8 + j) * AH + nt * 16 + m]);
      bfr[ks][nt] = bv;
    }
  float ubreg[4], w2reg[4];
#pragma unroll
  for (int nt = 0; nt < 4; ++nt) {
    ubreg[nt] = __shfl(upj, nt * 16 + m);
    w2reg[nt] = w2[nt * 16 + m];
  }
  const float b2v = b2[0];
  float arep[32];
#pragma unroll
  for (int c = 0; c < 32; ++c) arep[c] = 0.f;
  const int* hrow = user_history + (long)b * HLEN;
  for (int t = 0; t < NTILE; ++t) {
    const int row = t * 16 + m;
    const int idx = (row < HLEN) ? hrow[row] : 0;
    bf16x8 a[4];
    const float* rp = item_table + (long)idx * DIM;
#pragma unroll
    for (int ks = 0; ks < 4; ++ks) {
      f32x4 lo = *(const f32x4*)(rp + ks * 32 + g * 8);
      f32x4 hi = *(const f32x4*)(rp + ks * 32 + g * 8 + 4);
      bf16x8 av;
      av[0] = (short)f2bf(lo[0]); av[1] = (short)f2bf(lo[1]);
      av[2] = (short)f2bf(lo[2]); av[3] = (short)f2bf(lo[3]);
      av[4] = (short)f2bf(hi[0]); av[5] = (short)f2bf(hi[1]);
      av[6] = (short)f2bf(hi[2]); av[7] = (short)f2bf(hi[3]);
      a[ks] = av;
    }
    f32x4 acc[4];
#pragma unroll
    for (int nt = 0; nt < 4; ++nt) acc[nt] = (f32x4){0.f, 0.f, 0.f, 0.f};
#pragma unroll
    for (int ks = 0; ks < 4; ++ks)
#pragma unroll
      for (int nt = 0; nt < 4; ++nt)
        acc[nt] = __builtin_amdgcn_mfma_f32_16x16x32_bf16(a[ks], bfr[ks][nt], acc[nt], 0, 0, 0);
    float sums[4];
#pragma unroll
    for (int r = 0; r < 4; ++r) {
      float s = 0.f;
#pragma unroll
      for (int nt = 0; nt < 4; ++nt) {
        float h = fmaxf(acc[nt][r] + ubreg[nt], 0.f);
        s = fmaf(h, w2reg[nt], s);
      }
      s += __shfl_xor(s, 1); s += __shfl_xor(s, 2);
      s += __shfl_xor(s, 4); s += __shfl_xor(s, 8);
      sums[r] = s;
    }
    const int q = m & 3;
    float keep = (q == 0) ? sums[0] : (q == 1) ? sums[1] : (q == 2) ? sums[2] : sums[3];
    float sv = __shfl(keep, ((m >> 2) << 4) | m);
    float attw = 1.f / (1.f + __expf(-(sv + b2v)));
    if (row >= HLEN) attw = 0.f;
#pragma unroll
    for (int ks = 0; ks < 4; ++ks)
#pragma unroll
      for (int j = 0; j < 8; ++j)
        arep[ks * 8 + j] = fmaf(attw, bf2f((unsigned short)a[ks][j]), arep[ks * 8 + j]);
  }
#pragma unroll
  for (int c = 0; c < 32; ++c) {
    arep[c] += __shfl_xor(arep[c], 1);
    arep[c] += __shfl_xor(arep[c], 2);
    arep[c] += __shfl_xor(arep[c], 4);
    arep[c] += __shfl_xor(arep[c], 8);
  }
  if (m == 0) {
#pragma unroll
    for (int ks = 0; ks < 4; ++ks)
#pragma unroll
      for (int j = 0; j < 8; ++j) {
        const int col = ks * 32 + g * 8 + j;
        out_user[(long)b * DIM + col] = urow[col] + arep[ks * 8 + j];
      }
  }
}

// ---------------------------------------------------------------------------
extern "C" void kernel_launch(void* const* d_in, const int* in_sizes, int n_in,
                              void* d_out, int out_size, void* d_ws, size_t ws_size,
                              hipStream_t stream) {
  const int*   user_ids     = (const int*)d_in[0];
  const int*   item_ids     = (const int*)d_in[1];
  const int*   user_history = (const int*)d_in[2];
  const float* user_table   = (const float*)d_in[3];
  const float* item_table   = (const float*)d_in[4];
  const float* fi           = (const float*)d_in[5];
  const float* w1           = (const float*)d_in[6];
  const float* b1           = (const float*)d_in[7];
  const float* w2           = (const float*)d_in[8];
  const float* b2           = (const float*)d_in[9];

  float* out       = (float*)d_out;
  float* out_user  = out;
  float* out_item  = out + (size_t)NB * DIM;
  float* out_inter = out + (size_t)2 * NB * DIM;

  const size_t need = (size_t)NITEMS * DIM + 16384;
  if (ws_size >= need) {
    unsigned char* tbl8 = (unsigned char*)d_ws;
    unsigned char* w1a8 = tbl8 + (size_t)NITEMS * DIM;
    pre_kernel<<<INTER_BLKS + 1024, 256, 0, stream>>>(user_ids, item_ids, user_table,
        item_table, fi, w1, tbl8, w1a8, out_item, out_inter);
    main_kernel_fp8s<<<NB / 4, 256, 0, stream>>>(user_ids, user_history, user_table,
        tbl8, w1a8, b1, w2, b2, out_user);
  } else {
    main_fallback<<<NB / 4, 256, 0, stream>>>(user_ids, user_history, user_table,
        item_table, w1, b1, w2, b2, out_user);
    pre_kernel<<<INTER_BLKS, 256, 0, stream>>>(user_ids, item_ids, user_table,
        item_table, fi, w1, nullptr, nullptr, out_item, out_inter);
  }
}

// Round 6
// 109.118 us; speedup vs baseline: 1.1665x; 1.1665x over previous
//
#include <hip/hip_runtime.h>
#include <math.h>

#define NB      8192
#define HLEN    200
#define DIM     128
#define AH      64
#define NITEMS  100000
#define NTILE   13
#define INTER_BLKS (NB / 32)

typedef __attribute__((ext_vector_type(4))) float f32x4;
typedef __attribute__((ext_vector_type(2))) float f32x2;
typedef __attribute__((ext_vector_type(4))) int   i32x4;
typedef __attribute__((ext_vector_type(8))) short bf16x8;
typedef unsigned int uint;

__device__ __forceinline__ unsigned short f2bf(float f) {
  uint u = __float_as_uint(f);
  u += 0x7fffu + ((u >> 16) & 1u);
  return (unsigned short)(u >> 16);
}
__device__ __forceinline__ float bf2f(unsigned short h) {
  return __uint_as_float(((uint)h) << 16);
}
__device__ __forceinline__ long pick64(const i32x4& v, int h) {
  return (long)(unsigned)v[2 * h] | ((long)(unsigned)v[2 * h + 1] << 32);
}
__device__ __forceinline__ i32x4 ldnt(const void* p) {
  return __builtin_nontemporal_load((const i32x4*)p);
}

// ---------------------------------------------------------------------------
// Pre-kernel: blocks [0,INTER_BLKS) = bilinear interaction + item_emb copy
// (verified r1-r5 body); rest = item_table f32 -> fp8 e4m3 (row = 128B = one
// cache line) + w1 -> fp8 fragment table in the R2-VERIFIED layout:
//   w1f8[((((part*4+s)*4+nt)*16+m)*4+g)*8+j] = fp8(w1[kg][nt*16+m]),
//   kg = part*128 + (s>>1)*64 + g*16 + (s&1)*8 + j
// ---------------------------------------------------------------------------
__global__ __launch_bounds__(256)
void pre_kernel(const int* __restrict__ user_ids,
                const int* __restrict__ item_ids,
                const float* __restrict__ user_table,
                const float* __restrict__ item_table,
                const float* __restrict__ fi,
                const float* __restrict__ w1,
                unsigned char* __restrict__ tbl8,
                unsigned char* __restrict__ w1f8,
                float* __restrict__ out_item,
                float* __restrict__ out_inter) {
  const int t = threadIdx.x;
  if (blockIdx.x < INTER_BLKS) {
    __shared__ unsigned short fitb[DIM * 130];
    __shared__ float u4[4][DIM];
    __shared__ float red[4][4];
    for (int i = t; i < DIM * DIM; i += 256) {
      int d = i >> 7, e = i & 127;
      fitb[e * 130 + d] = f2bf(fi[i]);
    }
    const int col = t & 127;
    const int dh = t >> 7;
    const int lane = t & 63;
    const int wv = t >> 6;
    const int b0 = blockIdx.x * 32;
    const unsigned short* fr = &fitb[col * 130 + dh * 64];
    for (int grp = 0; grp < 8; ++grp) {
      __syncthreads();
      for (int i = t; i < 4 * DIM; i += 256) {
        int bi = i >> 7, d = i & 127;
        u4[bi][d] = user_table[(long)user_ids[b0 + grp * 4 + bi] * DIM + d];
      }
      __syncthreads();
      float a0 = 0.f, a1 = 0.f, a2 = 0.f, a3 = 0.f;
#pragma unroll 4
      for (int d = 0; d < 64; d += 4) {
        float f0 = bf2f(fr[d]), f1 = bf2f(fr[d + 1]), f2 = bf2f(fr[d + 2]), f3 = bf2f(fr[d + 3]);
        f32x4 q0 = *(const f32x4*)&u4[0][dh * 64 + d];
        f32x4 q1 = *(const f32x4*)&u4[1][dh * 64 + d];
        f32x4 q2 = *(const f32x4*)&u4[2][dh * 64 + d];
        f32x4 q3 = *(const f32x4*)&u4[3][dh * 64 + d];
        a0 = fmaf(f0, q0[0], a0); a0 = fmaf(f1, q0[1], a0); a0 = fmaf(f2, q0[2], a0); a0 = fmaf(f3, q0[3], a0);
        a1 = fmaf(f0, q1[0], a1); a1 = fmaf(f1, q1[1], a1); a1 = fmaf(f2, q1[2], a1); a1 = fmaf(f3, q1[3], a1);
        a2 = fmaf(f0, q2[0], a2); a2 = fmaf(f1, q2[1], a2); a2 = fmaf(f2, q2[2], a2); a2 = fmaf(f3, q2[3], a2);
        a3 = fmaf(f0, q3[0], a3); a3 = fmaf(f1, q3[1], a3); a3 = fmaf(f2, q3[2], a3); a3 = fmaf(f3, q3[3], a3);
      }
      const int bb = b0 + grp * 4;
      const float vv0 = item_table[(long)item_ids[bb + 0] * DIM + col];
      const float vv1 = item_table[(long)item_ids[bb + 1] * DIM + col];
      const float vv2 = item_table[(long)item_ids[bb + 2] * DIM + col];
      const float vv3 = item_table[(long)item_ids[bb + 3] * DIM + col];
      if (dh == 0) {
        out_item[(long)(bb + 0) * DIM + col] = vv0;
        out_item[(long)(bb + 1) * DIM + col] = vv1;
        out_item[(long)(bb + 2) * DIM + col] = vv2;
        out_item[(long)(bb + 3) * DIM + col] = vv3;
      }
      float p0 = a0 * vv0, p1 = a1 * vv1, p2 = a2 * vv2, p3 = a3 * vv3;
#pragma unroll
      for (int msk = 1; msk <= 32; msk <<= 1) {
        p0 += __shfl_xor(p0, msk);
        p1 += __shfl_xor(p1, msk);
        p2 += __shfl_xor(p2, msk);
        p3 += __shfl_xor(p3, msk);
      }
      if (lane == 0) { red[wv][0] = p0; red[wv][1] = p1; red[wv][2] = p2; red[wv][3] = p3; }
      __syncthreads();
      if (t < 4)
        out_inter[bb + t] = red[0][t] + red[1][t] + red[2][t] + red[3][t];
    }
  } else {
    const int cb = blockIdx.x - INTER_BLKS;
    const int cgrid = gridDim.x - INTER_BLKS;
    const long t0 = (long)cb * 256 + t;
    const long total4 = (long)NITEMS * DIM / 4;
    const long stride = (long)cgrid * 256;
    for (long i = t0; i < total4; i += stride) {
      f32x4 v = ((const f32x4*)item_table)[i];
      int p = __builtin_amdgcn_cvt_pk_fp8_f32(v[0], v[1], 0, false);
      p     = __builtin_amdgcn_cvt_pk_fp8_f32(v[2], v[3], p, true);
      ((int*)tbl8)[i] = p;
    }
    if (t0 < 16384) {
      int L = (int)t0;
      int j = L & 7, gg = (L >> 3) & 3, mm = (L >> 5) & 15;
      int nt = (L >> 9) & 3, s = (L >> 11) & 3, part = (L >> 13) & 1;
      int kg = part * 128 + (s >> 1) * 64 + gg * 16 + (s & 1) * 8 + j;
      float v = w1[kg * AH + nt * 16 + mm];
      int pk = __builtin_amdgcn_cvt_pk_fp8_f32(v, v, 0, false);
      w1f8[L] = (unsigned char)(pk & 0xff);
    }
  }
}

// ---------------------------------------------------------------------------
// Main kernel: r2-verified fp8 attention pooling + deeper gather pipeline.
// Ring: 5 buffers, prefetch distance 4 -> 8 gather-instrs in flight/wave
// (r2 had 4). First 4 tiles issued BEFORE the prologue so u-projection math
// hides their latency. Gathers are non-temporal (L1 bypass: 12.8MB random-
// access table has ~0% L1 hit rate).
// ---------------------------------------------------------------------------
__global__ __launch_bounds__(256)
void main_kernel_fp8(const int* __restrict__ user_ids,
                     const int* __restrict__ user_history,
                     const float* __restrict__ user_table,
                     const unsigned char* __restrict__ tbl8,
                     const unsigned char* __restrict__ w1f8,
                     const float* __restrict__ b1,
                     const float* __restrict__ w2,
                     const float* __restrict__ b2,
                     float* __restrict__ out_user) {
  const int lane = threadIdx.x & 63;
  const int wave = threadIdx.x >> 6;
  const int b = blockIdx.x * 4 + wave;
  const int m = lane & 15;
  const int g = lane >> 4;

  const int uid = __builtin_amdgcn_readfirstlane(user_ids[b]);
  const float* urow = user_table + (long)uid * DIM;
  const int* hrow = user_history + (long)b * HLEN;

  // ---- preload all history indices (independent loads, issued at once) ----
  int idxs[NTILE];
#pragma unroll
  for (int t = 0; t < NTILE; ++t) {
    int row = t * 16 + m;
    idxs[t] = (row < HLEN) ? hrow[row] : 0;
  }

  // ---- gather ring: 5 buffers, distance 4; first 4 issued immediately ----
  i32x4 pa[5][2];
#define LOADT(T, BUF)                                                          \
  {                                                                            \
    const unsigned char* p_ = tbl8 + ((long)idxs[T] << 7) + g * 16;            \
    pa[BUF][0] = ldnt(p_);                                                     \
    pa[BUF][1] = ldnt(p_ + 64);                                                \
  }
  LOADT(0, 0) LOADT(1, 1) LOADT(2, 2) LOADT(3, 3)

  // ---- u -> fp8 A-fragments (same (g,byte)->k map as history rows) ----
  i32x4 uf[2];
#pragma unroll
  for (int kb = 0; kb < 2; ++kb) {
    const float* up = urow + kb * 64 + g * 16;
    f32x4 q0 = *(const f32x4*)(up + 0);
    f32x4 q1 = *(const f32x4*)(up + 4);
    f32x4 q2 = *(const f32x4*)(up + 8);
    f32x4 q3 = *(const f32x4*)(up + 12);
    i32x4 d;
    d[0] = __builtin_amdgcn_cvt_pk_fp8_f32(q0[0], q0[1], 0, false);
    d[0] = __builtin_amdgcn_cvt_pk_fp8_f32(q0[2], q0[3], d[0], true);
    d[1] = __builtin_amdgcn_cvt_pk_fp8_f32(q1[0], q1[1], 0, false);
    d[1] = __builtin_amdgcn_cvt_pk_fp8_f32(q1[2], q1[3], d[1], true);
    d[2] = __builtin_amdgcn_cvt_pk_fp8_f32(q2[0], q2[1], 0, false);
    d[2] = __builtin_amdgcn_cvt_pk_fp8_f32(q2[2], q2[3], d[2], true);
    d[3] = __builtin_amdgcn_cvt_pk_fp8_f32(q3[0], q3[1], 0, false);
    d[3] = __builtin_amdgcn_cvt_pk_fp8_f32(q3[2], q3[3], d[3], true);
    uf[kb] = d;
  }

  const unsigned char* wtop = w1f8;
  const unsigned char* wbot = w1f8 + 8192;

  // ---- u-projection via MFMA: accu[nt][*] = (u @ w1_top)[nt*16+m] ----
  f32x4 accu[4];
#pragma unroll
  for (int nt = 0; nt < 4; ++nt) accu[nt] = (f32x4){0.f, 0.f, 0.f, 0.f};
#pragma unroll
  for (int s = 0; s < 4; ++s) {
    long a_s = pick64(uf[s >> 1], s & 1);
#pragma unroll
    for (int nt = 0; nt < 4; ++nt) {
      long bf = *(const long*)(wtop + ((s * 4 + nt) * 16 + m) * 32 + g * 8);
      accu[nt] = __builtin_amdgcn_mfma_f32_16x16x32_fp8_fp8(a_s, bf, accu[nt], 0, 0, 0);
    }
  }
  float ubreg[4], w2reg[4];
#pragma unroll
  for (int nt = 0; nt < 4; ++nt) {
    ubreg[nt] = accu[nt][0] + b1[nt * 16 + m];
    w2reg[nt] = w2[nt * 16 + m];
  }
  const float b2v = b2[0];

  // ---- W1 bottom fragments, held in registers (16 x 8B) ----
  long bfr[4][4];
#pragma unroll
  for (int s = 0; s < 4; ++s)
#pragma unroll
    for (int nt = 0; nt < 4; ++nt)
      bfr[s][nt] = *(const long*)(wbot + ((s * 4 + nt) * 16 + m) * 32 + g * 8);

  float arep[32];
#pragma unroll
  for (int c = 0; c < 32; ++c) arep[c] = 0.f;

  // ---- depth-5 pipelined main loop ----
#pragma unroll
  for (int t = 0; t < NTILE; ++t) {
    if (t + 4 < NTILE) LOADT(t + 4, (t + 4) % 5)
    const int cb = t % 5;

    f32x4 acc[4];
#pragma unroll
    for (int nt = 0; nt < 4; ++nt) acc[nt] = (f32x4){0.f, 0.f, 0.f, 0.f};
#pragma unroll
    for (int s = 0; s < 4; ++s) {
      long a_s = pick64(pa[cb][s >> 1], s & 1);
#pragma unroll
      for (int nt = 0; nt < 4; ++nt)
        acc[nt] = __builtin_amdgcn_mfma_f32_16x16x32_fp8_fp8(a_s, bfr[s][nt], acc[nt], 0, 0, 0);
    }

    // scores: acc[nt][r] = S[row=g*4+r][col=nt*16+m]; reduce over 16 lanes
    float sums[4];
#pragma unroll
    for (int r = 0; r < 4; ++r) {
      float s = 0.f;
#pragma unroll
      for (int nt = 0; nt < 4; ++nt) {
        float h = fmaxf(acc[nt][r] + ubreg[nt], 0.f);
        s = fmaf(h, w2reg[nt], s);
      }
      s += __shfl_xor(s, 1);
      s += __shfl_xor(s, 2);
      s += __shfl_xor(s, 4);
      s += __shfl_xor(s, 8);
      sums[r] = s;
    }
    // each lane needs the score of row m: keep sums[lane&3], one shfl
    const int q = m & 3;
    float keep = (q == 0) ? sums[0] : (q == 1) ? sums[1] : (q == 2) ? sums[2] : sums[3];
    float sv = __shfl(keep, ((m >> 2) << 4) | m);
    float attw = 1.f / (1.f + __expf(-(sv + b2v)));
    if (t * 16 + m >= HLEN) attw = 0.f;

    // attention-weighted accumulate: decode fp8 row bytes in-register
#pragma unroll
    for (int kb = 0; kb < 2; ++kb)
#pragma unroll
      for (int d = 0; d < 4; ++d) {
        f32x2 lo = __builtin_amdgcn_cvt_pk_f32_fp8(pa[cb][kb][d], false);
        f32x2 hi = __builtin_amdgcn_cvt_pk_f32_fp8(pa[cb][kb][d], true);
        const int base = kb * 16 + d * 4;
        arep[base + 0] = fmaf(attw, lo[0], arep[base + 0]);
        arep[base + 1] = fmaf(attw, lo[1], arep[base + 1]);
        arep[base + 2] = fmaf(attw, hi[0], arep[base + 2]);
        arep[base + 3] = fmaf(attw, hi[1], arep[base + 3]);
      }
  }
#undef LOADT

  // reduce over the 16 row-lanes of each group; lane m==0 writes 32 cols
#pragma unroll
  for (int c = 0; c < 32; ++c) {
    arep[c] += __shfl_xor(arep[c], 1);
    arep[c] += __shfl_xor(arep[c], 2);
    arep[c] += __shfl_xor(arep[c], 4);
    arep[c] += __shfl_xor(arep[c], 8);
  }
  if (m == 0) {
#pragma unroll
    for (int kb = 0; kb < 2; ++kb)
#pragma unroll
      for (int i4 = 0; i4 < 4; ++i4) {
        const int col = kb * 64 + g * 16 + i4 * 4;
        f32x4 uv = *(const f32x4*)(urow + col);
        f32x4 o;
#pragma unroll
        for (int qq = 0; qq < 4; ++qq) o[qq] = uv[qq] + arep[kb * 16 + i4 * 4 + qq];
        *(f32x4*)(out_user + (long)b * DIM + col) = o;
      }
  }
}

// ---------------------------------------------------------------------------
// Fallback (ws too small): r1 bf16-inline path, f32 table reads (verified).
// ---------------------------------------------------------------------------
__global__ __launch_bounds__(256)
void main_fallback(const int* __restrict__ user_ids,
                   const int* __restrict__ user_history,
                   const float* __restrict__ user_table,
                   const float* __restrict__ item_table,
                   const float* __restrict__ w1,
                   const float* __restrict__ b1,
                   const float* __restrict__ w2,
                   const float* __restrict__ b2,
                   float* __restrict__ out_user) {
  const int lane = threadIdx.x & 63;
  const int wave = threadIdx.x >> 6;
  const int b = blockIdx.x * 4 + wave;
  const int m = lane & 15, g = lane >> 4;
  const int uid = __builtin_amdgcn_readfirstlane(user_ids[b]);
  const float* urow = user_table + (long)uid * DIM;
  float upj = b1[lane];
#pragma unroll 8
  for (int d = 0; d < DIM; ++d) upj = fmaf(urow[d], w1[d * AH + lane], upj);
  bf16x8 bfr[4][4];
#pragma unroll
  for (int ks = 0; ks < 4; ++ks)
#pragma unroll
    for (int nt = 0; nt < 4; ++nt) {
      bf16x8 bv;
#pragma unroll
      for (int j = 0; j < 8; ++j)
        bv[j] = (short)f2bf(w1[(DIM + ks * 32 + g * 8 + j) * AH + nt * 16 + m]);
      bfr[ks][nt] = bv;
    }
  float ubreg[4], w2reg[4];
#pragma unroll
  for (int nt = 0; nt < 4; ++nt) {
    ubreg[nt] = __shfl(upj, nt * 16 + m);
    w2reg[nt] = w2[nt * 16 + m];
  }
  const float b2v = b2[0];
  float arep[32];
#pragma unroll
  for (int c = 0; c < 32; ++c) arep[c] = 0.f;
  const int* hrow = user_history + (long)b * HLEN;
  for (int t = 0; t < NTILE; ++t) {
    const int row = t * 16 + m;
    const int idx = (row < HLEN) ? hrow[row] : 0;
    bf16x8 a[4];
    const float* rp = item_table + (long)idx * DIM;
#pragma unroll
    for (int ks = 0; ks < 4; ++ks) {
      f32x4 lo = *(const f32x4*)(rp + ks * 32 + g * 8);
      f32x4 hi = *(const f32x4*)(rp + ks * 32 + g * 8 + 4);
      bf16x8 av;
      av[0] = (short)f2bf(lo[0]); av[1] = (short)f2bf(lo[1]);
      av[2] = (short)f2bf(lo[2]); av[3] = (short)f2bf(lo[3]);
      av[4] = (short)f2bf(hi[0]); av[5] = (short)f2bf(hi[1]);
      av[6] = (short)f2bf(hi[2]); av[7] = (short)f2bf(hi[3]);
      a[ks] = av;
    }
    f32x4 acc[4];
#pragma unroll
    for (int nt = 0; nt < 4; ++nt) acc[nt] = (f32x4){0.f, 0.f, 0.f, 0.f};
#pragma unroll
    for (int ks = 0; ks < 4; ++ks)
#pragma unroll
      for (int nt = 0; nt < 4; ++nt)
        acc[nt] = __builtin_amdgcn_mfma_f32_16x16x32_bf16(a[ks], bfr[ks][nt], acc[nt], 0, 0, 0);
    float sums[4];
#pragma unroll
    for (int r = 0; r < 4; ++r) {
      float s = 0.f;
#pragma unroll
      for (int nt = 0; nt < 4; ++nt) {
        float h = fmaxf(acc[nt][r] + ubreg[nt], 0.f);
        s = fmaf(h, w2reg[nt], s);
      }
      s += __shfl_xor(s, 1); s += __shfl_xor(s, 2);
      s += __shfl_xor(s, 4); s += __shfl_xor(s, 8);
      sums[r] = s;
    }
    const int q = m & 3;
    float keep = (q == 0) ? sums[0] : (q == 1) ? sums[1] : (q == 2) ? sums[2] : sums[3];
    float sv = __shfl(keep, ((m >> 2) << 4) | m);
    float attw = 1.f / (1.f + __expf(-(sv + b2v)));
    if (row >= HLEN) attw = 0.f;
#pragma unroll
    for (int ks = 0; ks < 4; ++ks)
#pragma unroll
      for (int j = 0; j < 8; ++j)
        arep[ks * 8 + j] = fmaf(attw, bf2f((unsigned short)a[ks][j]), arep[ks * 8 + j]);
  }
#pragma unroll
  for (int c = 0; c < 32; ++c) {
    arep[c] += __shfl_xor(arep[c], 1);
    arep[c] += __shfl_xor(arep[c], 2);
    arep[c] += __shfl_xor(arep[c], 4);
    arep[c] += __shfl_xor(arep[c], 8);
  }
  if (m == 0) {
#pragma unroll
    for (int ks = 0; ks < 4; ++ks)
#pragma unroll
      for (int j = 0; j < 8; ++j) {
        const int col = ks * 32 + g * 8 + j;
        out_user[(long)b * DIM + col] = urow[col] + arep[ks * 8 + j];
      }
  }
}

// ---------------------------------------------------------------------------
extern "C" void kernel_launch(void* const* d_in, const int* in_sizes, int n_in,
                              void* d_out, int out_size, void* d_ws, size_t ws_size,
                              hipStream_t stream) {
  const int*   user_ids     = (const int*)d_in[0];
  const int*   item_ids     = (const int*)d_in[1];
  const int*   user_history = (const int*)d_in[2];
  const float* user_table   = (const float*)d_in[3];
  const float* item_table   = (const float*)d_in[4];
  const float* fi           = (const float*)d_in[5];
  const float* w1           = (const float*)d_in[6];
  const float* b1           = (const float*)d_in[7];
  const float* w2           = (const float*)d_in[8];
  const float* b2           = (const float*)d_in[9];

  float* out       = (float*)d_out;
  float* out_user  = out;
  float* out_item  = out + (size_t)NB * DIM;
  float* out_inter = out + (size_t)2 * NB * DIM;

  const size_t need = (size_t)NITEMS * DIM + 16384;
  if (ws_size >= need) {
    unsigned char* tbl8 = (unsigned char*)d_ws;
    unsigned char* w1f8 = tbl8 + (size_t)NITEMS * DIM;
    pre_kernel<<<INTER_BLKS + 1024, 256, 0, stream>>>(user_ids, item_ids, user_table,
        item_table, fi, w1, tbl8, w1f8, out_item, out_inter);
    main_kernel_fp8<<<NB / 4, 256, 0, stream>>>(user_ids, user_history, user_table,
        tbl8, w1f8, b1, w2, b2, out_user);
  } else {
    main_fallback<<<NB / 4, 256, 0, stream>>>(user_ids, user_history, user_table,
        item_table, w1, b1, w2, b2, out_user);
    pre_kernel<<<INTER_BLKS, 256, 0, stream>>>(user_ids, item_ids, user_table,
        item_table, fi, w1, nullptr, nullptr, out_item, out_inter);
  }
}

// Round 7
// 99.437 us; speedup vs baseline: 1.2801x; 1.0974x over previous
//
#include <hip/hip_runtime.h>
#include <math.h>

#define NB      8192
#define HLEN    200
#define DIM     128
#define AH      64
#define NITEMS  100000
#define NTILE   13
#define GRP_BLKS (NB / 4)     // 2048 inter blocks (one 4-batch group each)
#define CONV_BLKS 1024

typedef __attribute__((ext_vector_type(4))) float f32x4;
typedef __attribute__((ext_vector_type(2))) float f32x2;
typedef __attribute__((ext_vector_type(4))) int   i32x4;
typedef __attribute__((ext_vector_type(8))) short bf16x8;
typedef unsigned int uint;

__device__ __forceinline__ unsigned short f2bf(float f) {
  uint u = __float_as_uint(f);
  u += 0x7fffu + ((u >> 16) & 1u);
  return (unsigned short)(u >> 16);
}
__device__ __forceinline__ float bf2f(unsigned short h) {
  return __uint_as_float(((uint)h) << 16);
}
__device__ __forceinline__ long pick64(const i32x4& v, int h) {
  return (long)(unsigned)v[2 * h] | ((long)(unsigned)v[2 * h + 1] << 32);
}
// async global->LDS, 16B per lane; LDS dest = wave-uniform base + lane*16,
// global src is per-lane (carries the row gather + seg swizzle).
__device__ __forceinline__ void gld16(const unsigned char* g, unsigned char* l) {
  __builtin_amdgcn_global_load_lds(
      (const __attribute__((address_space(1))) unsigned int*)g,
      (__attribute__((address_space(3))) unsigned int*)l, 16, 0, 0);
}

// ---------------------------------------------------------------------------
// Pre-kernel. Blocks [0, GRP_BLKS): bilinear interaction + item copy, ONE
// group of 4 batch elements per block (r6's 8-group serial block was a ~9us
// chain stretched 3x by co-running convert blocks). Blocks [GRP_BLKS, +CONV):
// item_table f32 -> fp8 e4m3 (row = 128B = one line) + w1 -> fp8 fragment
// table in the r2-verified layout.
// ---------------------------------------------------------------------------
__global__ __launch_bounds__(256)
void pre_kernel(const int* __restrict__ user_ids,
                const int* __restrict__ item_ids,
                const float* __restrict__ user_table,
                const float* __restrict__ item_table,
                const float* __restrict__ fi,
                const float* __restrict__ w1,
                unsigned char* __restrict__ tbl8,
                unsigned char* __restrict__ w1f8,
                float* __restrict__ out_item,
                float* __restrict__ out_inter) {
  const int t = threadIdx.x;
  if (blockIdx.x < GRP_BLKS) {
    __shared__ unsigned short fitb[DIM * 130];
    __shared__ float u4[4][DIM];
    __shared__ float red[4][4];
    for (int i = t; i < DIM * DIM; i += 256) {
      int d = i >> 7, e = i & 127;
      fitb[e * 130 + d] = f2bf(fi[i]);
    }
    const int col = t & 127;
    const int dh = t >> 7;
    const int lane = t & 63;
    const int wv = t >> 6;
    const int bb = blockIdx.x * 4;
    for (int i = t; i < 4 * DIM; i += 256) {
      int bi = i >> 7, d = i & 127;
      u4[bi][d] = user_table[(long)user_ids[bb + bi] * DIM + d];
    }
    __syncthreads();
    const unsigned short* fr = &fitb[col * 130 + dh * 64];
    float a0 = 0.f, a1 = 0.f, a2 = 0.f, a3 = 0.f;
#pragma unroll 4
    for (int d = 0; d < 64; d += 4) {
      float f0 = bf2f(fr[d]), f1 = bf2f(fr[d + 1]), f2 = bf2f(fr[d + 2]), f3 = bf2f(fr[d + 3]);
      f32x4 q0 = *(const f32x4*)&u4[0][dh * 64 + d];
      f32x4 q1 = *(const f32x4*)&u4[1][dh * 64 + d];
      f32x4 q2 = *(const f32x4*)&u4[2][dh * 64 + d];
      f32x4 q3 = *(const f32x4*)&u4[3][dh * 64 + d];
      a0 = fmaf(f0, q0[0], a0); a0 = fmaf(f1, q0[1], a0); a0 = fmaf(f2, q0[2], a0); a0 = fmaf(f3, q0[3], a0);
      a1 = fmaf(f0, q1[0], a1); a1 = fmaf(f1, q1[1], a1); a1 = fmaf(f2, q1[2], a1); a1 = fmaf(f3, q1[3], a1);
      a2 = fmaf(f0, q2[0], a2); a2 = fmaf(f1, q2[1], a2); a2 = fmaf(f2, q2[2], a2); a2 = fmaf(f3, q2[3], a2);
      a3 = fmaf(f0, q3[0], a3); a3 = fmaf(f1, q3[1], a3); a3 = fmaf(f2, q3[2], a3); a3 = fmaf(f3, q3[3], a3);
    }
    const float vv0 = item_table[(long)item_ids[bb + 0] * DIM + col];
    const float vv1 = item_table[(long)item_ids[bb + 1] * DIM + col];
    const float vv2 = item_table[(long)item_ids[bb + 2] * DIM + col];
    const float vv3 = item_table[(long)item_ids[bb + 3] * DIM + col];
    if (dh == 0) {
      out_item[(long)(bb + 0) * DIM + col] = vv0;
      out_item[(long)(bb + 1) * DIM + col] = vv1;
      out_item[(long)(bb + 2) * DIM + col] = vv2;
      out_item[(long)(bb + 3) * DIM + col] = vv3;
    }
    float p0 = a0 * vv0, p1 = a1 * vv1, p2 = a2 * vv2, p3 = a3 * vv3;
#pragma unroll
    for (int msk = 1; msk <= 32; msk <<= 1) {
      p0 += __shfl_xor(p0, msk);
      p1 += __shfl_xor(p1, msk);
      p2 += __shfl_xor(p2, msk);
      p3 += __shfl_xor(p3, msk);
    }
    if (lane == 0) { red[wv][0] = p0; red[wv][1] = p1; red[wv][2] = p2; red[wv][3] = p3; }
    __syncthreads();
    if (t < 4)
      out_inter[bb + t] = red[0][t] + red[1][t] + red[2][t] + red[3][t];
  } else {
    const int cb = blockIdx.x - GRP_BLKS;
    const long t0 = (long)cb * 256 + t;
    const long total4 = (long)NITEMS * DIM / 4;
    const long stride = (long)CONV_BLKS * 256;
    for (long i = t0; i < total4; i += stride) {
      f32x4 v = ((const f32x4*)item_table)[i];
      int p = __builtin_amdgcn_cvt_pk_fp8_f32(v[0], v[1], 0, false);
      p     = __builtin_amdgcn_cvt_pk_fp8_f32(v[2], v[3], p, true);
      ((int*)tbl8)[i] = p;
    }
    if (t0 < 16384) {
      int L = (int)t0;
      int j = L & 7, gg = (L >> 3) & 3, mm = (L >> 5) & 15;
      int nt = (L >> 9) & 3, s = (L >> 11) & 3, part = (L >> 13) & 1;
      int kg = part * 128 + (s >> 1) * 64 + gg * 16 + (s & 1) * 8 + j;
      float v = w1[kg * AH + nt * 16 + mm];
      int pk = __builtin_amdgcn_cvt_pk_fp8_f32(v, v, 0, false);
      w1f8[L] = (unsigned char)(pk & 0xff);
    }
  }
}

// ---------------------------------------------------------------------------
// Main kernel: fp8 attention pooling with LDS-staged gathers.
// Per wave (1 batch elem): 5-tile LDS window (2KB/tile), global_load_lds
// stages 8 rows per instruction (per-lane src addr = gather + seg-swizzle,
// linear LDS dest). Hand-counted vmcnt keeps 10 loads in flight; no
// __syncthreads anywhere (waves own disjoint LDS slices). Reissue into the
// just-consumed buffer only after lgkmcnt(0) retires this tile's ds_reads.
// Bias is seeded into the MFMA accumulator (C-in).
// ---------------------------------------------------------------------------
__global__ __launch_bounds__(256)
void main_kernel_fp8(const int* __restrict__ user_ids,
                     const int* __restrict__ user_history,
                     const float* __restrict__ user_table,
                     const unsigned char* __restrict__ tbl8,
                     const unsigned char* __restrict__ w1f8,
                     const float* __restrict__ b1,
                     const float* __restrict__ w2,
                     const float* __restrict__ b2,
                     float* __restrict__ out_user) {
  __shared__ unsigned char stg[4][5 * 2048];   // 40KB/block -> 4 blocks/CU
  const int lane = threadIdx.x & 63;
  const int wave = threadIdx.x >> 6;
  const int b = blockIdx.x * 4 + wave;
  const int m = lane & 15;
  const int g = lane >> 4;
  unsigned char* mystg = &stg[wave][0];

  const int uid = __builtin_amdgcn_readfirstlane(user_ids[b]);
  const float* urow = user_table + (long)uid * DIM;
  const int* hrow = user_history + (long)b * HLEN;

  // 1. history indices (lane m holds idx of rows t*16+m)
  int idxs[NTILE];
#pragma unroll
  for (int t = 0; t < NTILE; ++t) {
    int row = t * 16 + m;
    idxs[t] = (row < HLEN) ? hrow[row] : 0;
  }

  // 2. urow vector loads (issued BEFORE staging so their waits don't drain it)
  f32x4 uq[8];
#pragma unroll
  for (int kb = 0; kb < 2; ++kb)
#pragma unroll
    for (int j = 0; j < 4; ++j)
      uq[kb * 4 + j] = *(const f32x4*)(urow + kb * 64 + g * 16 + 4 * j);

  // 3. weight fragments + biases (also before staging)
  const unsigned char* wtop = w1f8;
  const unsigned char* wbot = w1f8 + 8192;
  long wt[4][4], bfr[4][4];
#pragma unroll
  for (int s = 0; s < 4; ++s)
#pragma unroll
    for (int nt = 0; nt < 4; ++nt) {
      wt[s][nt]  = *(const long*)(wtop + ((s * 4 + nt) * 16 + m) * 32 + g * 8);
      bfr[s][nt] = *(const long*)(wbot + ((s * 4 + nt) * 16 + m) * 32 + g * 8);
    }
  float b1reg[4], w2reg[4];
#pragma unroll
  for (int nt = 0; nt < 4; ++nt) {
    b1reg[nt] = b1[nt * 16 + m];
    w2reg[nt] = w2[nt * 16 + m];
  }
  const float b2v = b2[0];

  // 4. stage tiles 0..4 (per-lane src: row = shfl'd idx, seg pre-swizzled)
  const unsigned swg = (unsigned)(((lane & 7) ^ (lane >> 3)) << 4);
#define LOADT(T)                                                               \
  {                                                                            \
    int r0_ = __shfl(idxs[T], lane >> 3);                                      \
    int r1_ = __shfl(idxs[T], 8 + (lane >> 3));                                \
    unsigned char* l0_ = mystg + ((T) % 5) * 2048;                             \
    gld16(tbl8 + ((long)r0_ << 7) + swg, l0_);                                 \
    gld16(tbl8 + ((long)r1_ << 7) + swg, l0_ + 1024);                          \
  }
  LOADT(0) LOADT(1) LOADT(2) LOADT(3) LOADT(4)

  // 5. u -> fp8 fragments (hides under staging latency)
  i32x4 uf[2];
#pragma unroll
  for (int kb = 0; kb < 2; ++kb) {
    i32x4 d;
    d[0] = __builtin_amdgcn_cvt_pk_fp8_f32(uq[kb*4+0][0], uq[kb*4+0][1], 0, false);
    d[0] = __builtin_amdgcn_cvt_pk_fp8_f32(uq[kb*4+0][2], uq[kb*4+0][3], d[0], true);
    d[1] = __builtin_amdgcn_cvt_pk_fp8_f32(uq[kb*4+1][0], uq[kb*4+1][1], 0, false);
    d[1] = __builtin_amdgcn_cvt_pk_fp8_f32(uq[kb*4+1][2], uq[kb*4+1][3], d[1], true);
    d[2] = __builtin_amdgcn_cvt_pk_fp8_f32(uq[kb*4+2][0], uq[kb*4+2][1], 0, false);
    d[2] = __builtin_amdgcn_cvt_pk_fp8_f32(uq[kb*4+2][2], uq[kb*4+2][3], d[2], true);
    d[3] = __builtin_amdgcn_cvt_pk_fp8_f32(uq[kb*4+3][0], uq[kb*4+3][1], 0, false);
    d[3] = __builtin_amdgcn_cvt_pk_fp8_f32(uq[kb*4+3][2], uq[kb*4+3][3], d[3], true);
    uf[kb] = d;
  }

  // 6. u-projection via MFMA; ubreg = (u @ w1_top) + b1
  f32x4 accu[4];
#pragma unroll
  for (int nt = 0; nt < 4; ++nt) accu[nt] = (f32x4){0.f, 0.f, 0.f, 0.f};
#pragma unroll
  for (int s = 0; s < 4; ++s) {
    long a_s = pick64(uf[s >> 1], s & 1);
#pragma unroll
    for (int nt = 0; nt < 4; ++nt)
      accu[nt] = __builtin_amdgcn_mfma_f32_16x16x32_fp8_fp8(a_s, wt[s][nt], accu[nt], 0, 0, 0);
  }
  float ubreg[4];
#pragma unroll
  for (int nt = 0; nt < 4; ++nt) ubreg[nt] = accu[nt][0] + b1reg[nt];

  float arep[32];
#pragma unroll
  for (int c = 0; c < 32; ++c) arep[c] = 0.f;

  const unsigned sw0 = (unsigned)((g ^ (m & 7)) << 4);

#define STEP(T, WN, ISS)                                                       \
  {                                                                            \
    asm volatile("s_waitcnt vmcnt(" WN ")" ::: "memory");                      \
    __builtin_amdgcn_sched_barrier(0);                                         \
    const unsigned char* rp_ = mystg + ((T) % 5) * 2048 + (m << 7);            \
    i32x4 pa0 = *(const i32x4*)(rp_ + sw0);                                    \
    i32x4 pa1 = *(const i32x4*)(rp_ + (sw0 ^ 64));                             \
    f32x4 acc[4];                                                              \
    _Pragma("unroll")                                                          \
    for (int nt = 0; nt < 4; ++nt)                                             \
      acc[nt] = (f32x4){ubreg[nt], ubreg[nt], ubreg[nt], ubreg[nt]};           \
    _Pragma("unroll")                                                          \
    for (int s = 0; s < 4; ++s) {                                              \
      long a_s = pick64((s < 2) ? pa0 : pa1, s & 1);                           \
      _Pragma("unroll")                                                        \
      for (int nt = 0; nt < 4; ++nt)                                           \
        acc[nt] = __builtin_amdgcn_mfma_f32_16x16x32_fp8_fp8(a_s, bfr[s][nt], acc[nt], 0, 0, 0); \
    }                                                                          \
    float sums[4];                                                             \
    _Pragma("unroll")                                                          \
    for (int r = 0; r < 4; ++r) {                                              \
      float s_ = fmaxf(acc[0][r], 0.f) * w2reg[0];                             \
      s_ = fmaf(fmaxf(acc[1][r], 0.f), w2reg[1], s_);                          \
      s_ = fmaf(fmaxf(acc[2][r], 0.f), w2reg[2], s_);                          \
      s_ = fmaf(fmaxf(acc[3][r], 0.f), w2reg[3], s_);                          \
      s_ += __shfl_xor(s_, 1);                                                 \
      s_ += __shfl_xor(s_, 2);                                                 \
      s_ += __shfl_xor(s_, 4);                                                 \
      s_ += __shfl_xor(s_, 8);                                                 \
      sums[r] = s_;                                                            \
    }                                                                          \
    const int q_ = m & 3;                                                      \
    float keep_ = (q_ == 0) ? sums[0] : (q_ == 1) ? sums[1]                    \
                 : (q_ == 2) ? sums[2] : sums[3];                              \
    float sv_ = __shfl(keep_, ((m >> 2) << 4) | m);                            \
    float attw = 1.f / (1.f + __expf(-(sv_ + b2v)));                           \
    if ((T) * 16 + m >= HLEN) attw = 0.f;                                      \
    _Pragma("unroll")                                                          \
    for (int d = 0; d < 4; ++d) {                                              \
      f32x2 lo0 = __builtin_amdgcn_cvt_pk_f32_fp8(pa0[d], false);              \
      f32x2 hi0 = __builtin_amdgcn_cvt_pk_f32_fp8(pa0[d], true);               \
      arep[d * 4 + 0] = fmaf(attw, lo0[0], arep[d * 4 + 0]);                   \
      arep[d * 4 + 1] = fmaf(attw, lo0[1], arep[d * 4 + 1]);                   \
      arep[d * 4 + 2] = fmaf(attw, hi0[0], arep[d * 4 + 2]);                   \
      arep[d * 4 + 3] = fmaf(attw, hi0[1], arep[d * 4 + 3]);                   \
      f32x2 lo1 = __builtin_amdgcn_cvt_pk_f32_fp8(pa1[d], false);              \
      f32x2 hi1 = __builtin_amdgcn_cvt_pk_f32_fp8(pa1[d], true);               \
      arep[16 + d * 4 + 0] = fmaf(attw, lo1[0], arep[16 + d * 4 + 0]);         \
      arep[16 + d * 4 + 1] = fmaf(attw, lo1[1], arep[16 + d * 4 + 1]);         \
      arep[16 + d * 4 + 2] = fmaf(attw, hi1[0], arep[16 + d * 4 + 2]);         \
      arep[16 + d * 4 + 3] = fmaf(attw, hi1[1], arep[16 + d * 4 + 3]);         \
    }                                                                          \
    if ((ISS) < NTILE) {                                                       \
      asm volatile("s_waitcnt lgkmcnt(0)" ::: "memory");                       \
      __builtin_amdgcn_sched_barrier(0);                                       \
      LOADT(ISS);                                                              \
    }                                                                          \
  }

  STEP(0, "8", 5)  STEP(1, "8", 6)  STEP(2, "8", 7)  STEP(3, "8", 8)
  STEP(4, "8", 9)  STEP(5, "8", 10) STEP(6, "8", 11) STEP(7, "8", 12)
  STEP(8, "8", 13) STEP(9, "6", 13) STEP(10, "4", 13) STEP(11, "2", 13)
  STEP(12, "0", 13)
#undef STEP
#undef LOADT

  // reduce over the 16 row-lanes of each group; lane m==0 writes 32 cols
#pragma unroll
  for (int c = 0; c < 32; ++c) {
    arep[c] += __shfl_xor(arep[c], 1);
    arep[c] += __shfl_xor(arep[c], 2);
    arep[c] += __shfl_xor(arep[c], 4);
    arep[c] += __shfl_xor(arep[c], 8);
  }
  if (m == 0) {
#pragma unroll
    for (int kb = 0; kb < 2; ++kb)
#pragma unroll
      for (int i4 = 0; i4 < 4; ++i4) {
        const int col = kb * 64 + g * 16 + i4 * 4;
        f32x4 uv = *(const f32x4*)(urow + col);
        f32x4 o;
#pragma unroll
        for (int qq = 0; qq < 4; ++qq) o[qq] = uv[qq] + arep[kb * 16 + i4 * 4 + qq];
        *(f32x4*)(out_user + (long)b * DIM + col) = o;
      }
  }
}

// ---------------------------------------------------------------------------
// Fallback (ws too small): r1 bf16-inline path, f32 table reads (verified).
// ---------------------------------------------------------------------------
__global__ __launch_bounds__(256)
void main_fallback(const int* __restrict__ user_ids,
                   const int* __restrict__ user_history,
                   const float* __restrict__ user_table,
                   const float* __restrict__ item_table,
                   const float* __restrict__ w1,
                   const float* __restrict__ b1,
                   const float* __restrict__ w2,
                   const float* __restrict__ b2,
                   float* __restrict__ out_user) {
  const int lane = threadIdx.x & 63;
  const int wave = threadIdx.x >> 6;
  const int b = blockIdx.x * 4 + wave;
  const int m = lane & 15, g = lane >> 4;
  const int uid = __builtin_amdgcn_readfirstlane(user_ids[b]);
  const float* urow = user_table + (long)uid * DIM;
  float upj = b1[lane];
#pragma unroll 8
  for (int d = 0; d < DIM; ++d) upj = fmaf(urow[d], w1[d * AH + lane], upj);
  bf16x8 bfr[4][4];
#pragma unroll
  for (int ks = 0; ks < 4; ++ks)
#pragma unroll
    for (int nt = 0; nt < 4; ++nt) {
      bf16x8 bv;
#pragma unroll
      for (int j = 0; j < 8; ++j)
        bv[j] = (short)f2bf(w1[(DIM + ks * 32 + g * 8 + j) * AH + nt * 16 + m]);
      bfr[ks][nt] = bv;
    }
  float ubreg[4], w2reg[4];
#pragma unroll
  for (int nt = 0; nt < 4; ++nt) {
    ubreg[nt] = __shfl(upj, nt * 16 + m);
    w2reg[nt] = w2[nt * 16 + m];
  }
  const float b2v = b2[0];
  float arep[32];
#pragma unroll
  for (int c = 0; c < 32; ++c) arep[c] = 0.f;
  const int* hrow = user_history + (long)b * HLEN;
  for (int t = 0; t < NTILE; ++t) {
    const int row = t * 16 + m;
    const int idx = (row < HLEN) ? hrow[row] : 0;
    bf16x8 a[4];
    const float* rp = item_table + (long)idx * DIM;
#pragma unroll
    for (int ks = 0; ks < 4; ++ks) {
      f32x4 lo = *(const f32x4*)(rp + ks * 32 + g * 8);
      f32x4 hi = *(const f32x4*)(rp + ks * 32 + g * 8 + 4);
      bf16x8 av;
      av[0] = (short)f2bf(lo[0]); av[1] = (short)f2bf(lo[1]);
      av[2] = (short)f2bf(lo[2]); av[3] = (short)f2bf(lo[3]);
      av[4] = (short)f2bf(hi[0]); av[5] = (short)f2bf(hi[1]);
      av[6] = (short)f2bf(hi[2]); av[7] = (short)f2bf(hi[3]);
      a[ks] = av;
    }
    f32x4 acc[4];
#pragma unroll
    for (int nt = 0; nt < 4; ++nt) acc[nt] = (f32x4){0.f, 0.f, 0.f, 0.f};
#pragma unroll
    for (int ks = 0; ks < 4; ++ks)
#pragma unroll
      for (int nt = 0; nt < 4; ++nt)
        acc[nt] = __builtin_amdgcn_mfma_f32_16x16x32_bf16(a[ks], bfr[ks][nt], acc[nt], 0, 0, 0);
    float sums[4];
#pragma unroll
    for (int r = 0; r < 4; ++r) {
      float s = 0.f;
#pragma unroll
      for (int nt = 0; nt < 4; ++nt) {
        float h = fmaxf(acc[nt][r] + ubreg[nt], 0.f);
        s = fmaf(h, w2reg[nt], s);
      }
      s += __shfl_xor(s, 1); s += __shfl_xor(s, 2);
      s += __shfl_xor(s, 4); s += __shfl_xor(s, 8);
      sums[r] = s;
    }
    const int q = m & 3;
    float keep = (q == 0) ? sums[0] : (q == 1) ? sums[1] : (q == 2) ? sums[2] : sums[3];
    float sv = __shfl(keep, ((m >> 2) << 4) | m);
    float attw = 1.f / (1.f + __expf(-(sv + b2v)));
    if (row >= HLEN) attw = 0.f;
#pragma unroll
    for (int ks = 0; ks < 4; ++ks)
#pragma unroll
      for (int j = 0; j < 8; ++j)
        arep[ks * 8 + j] = fmaf(attw, bf2f((unsigned short)a[ks][j]), arep[ks * 8 + j]);
  }
#pragma unroll
  for (int c = 0; c < 32; ++c) {
    arep[c] += __shfl_xor(arep[c], 1);
    arep[c] += __shfl_xor(arep[c], 2);
    arep[c] += __shfl_xor(arep[c], 4);
    arep[c] += __shfl_xor(arep[c], 8);
  }
  if (m == 0) {
#pragma unroll
    for (int ks = 0; ks < 4; ++ks)
#pragma unroll
      for (int j = 0; j < 8; ++j) {
        const int col = ks * 32 + g * 8 + j;
        out_user[(long)b * DIM + col] = urow[col] + arep[ks * 8 + j];
      }
  }
}

// ---------------------------------------------------------------------------
extern "C" void kernel_launch(void* const* d_in, const int* in_sizes, int n_in,
                              void* d_out, int out_size, void* d_ws, size_t ws_size,
                              hipStream_t stream) {
  const int*   user_ids     = (const int*)d_in[0];
  const int*   item_ids     = (const int*)d_in[1];
  const int*   user_history = (const int*)d_in[2];
  const float* user_table   = (const float*)d_in[3];
  const float* item_table   = (const float*)d_in[4];
  const float* fi           = (const float*)d_in[5];
  const float* w1           = (const float*)d_in[6];
  const float* b1           = (const float*)d_in[7];
  const float* w2           = (const float*)d_in[8];
  const float* b2           = (const float*)d_in[9];

  float* out       = (float*)d_out;
  float* out_user  = out;
  float* out_item  = out + (size_t)NB * DIM;
  float* out_inter = out + (size_t)2 * NB * DIM;

  const size_t need = (size_t)NITEMS * DIM + 16384;
  if (ws_size >= need) {
    unsigned char* tbl8 = (unsigned char*)d_ws;
    unsigned char* w1f8 = tbl8 + (size_t)NITEMS * DIM;
    pre_kernel<<<GRP_BLKS + CONV_BLKS, 256, 0, stream>>>(user_ids, item_ids, user_table,
        item_table, fi, w1, tbl8, w1f8, out_item, out_inter);
    main_kernel_fp8<<<NB / 4, 256, 0, stream>>>(user_ids, user_history, user_table,
        tbl8, w1f8, b1, w2, b2, out_user);
  } else {
    main_fallback<<<NB / 4, 256, 0, stream>>>(user_ids, user_history, user_table,
        item_table, w1, b1, w2, b2, out_user);
    pre_kernel<<<GRP_BLKS, 256, 0, stream>>>(user_ids, item_ids, user_table,
        item_table, fi, w1, nullptr, nullptr, out_item, out_inter);
  }
}